// Round 1
// baseline (379.865 us; speedup 1.0000x reference)
//
#include <hip/hip_runtime.h>

#define N 1024
#define DIM 2048

typedef unsigned long long u64;

__device__ __forceinline__ u64 umin64(u64 a, u64 b){ return a < b ? a : b; }

// ---------------- row norms ----------------
__global__ __launch_bounds__(256) void rownorm_kernel(const float* __restrict__ x, float* __restrict__ xx){
  int i = blockIdx.x, t = threadIdx.x;
  const float4* row = (const float4*)(x + (size_t)i * DIM);
  float s = 0.f;
  #pragma unroll
  for (int q = 0; q < 2; q++){
    float4 v = row[t + q*256];
    s += v.x*v.x + v.y*v.y + v.z*v.z + v.w*v.w;
  }
  #pragma unroll
  for (int off = 32; off > 0; off >>= 1) s += __shfl_down(s, off);
  __shared__ float sm[4];
  if ((t & 63) == 0) sm[t >> 6] = s;
  __syncthreads();
  if (t == 0) xx[i] = sm[0] + sm[1] + sm[2] + sm[3];
}

// ---------------- D0 = clamp(xx_i + xx_j - 2*x@x^T, 0) ----------------
__global__ __launch_bounds__(256) void gemm_dist_kernel(const float* __restrict__ x,
                                                        const float* __restrict__ xx,
                                                        float* __restrict__ D){
  __shared__ float As[32][68];
  __shared__ float Bs[32][68];
  int t = threadIdx.x;
  int tx = t & 15, ty = t >> 4;
  int i0 = blockIdx.y * 64, j0 = blockIdx.x * 64;
  float acc[4][4] = {};
  for (int k0 = 0; k0 < DIM; k0 += 32){
    #pragma unroll
    for (int e = 0; e < 8; e++){
      int idx = t + e*256;
      int r = idx >> 5, c = idx & 31;
      As[c][r] = x[(size_t)(i0 + r) * DIM + k0 + c];
      Bs[c][r] = x[(size_t)(j0 + r) * DIM + k0 + c];
    }
    __syncthreads();
    #pragma unroll
    for (int kk = 0; kk < 32; kk++){
      float4 a4 = *(const float4*)&As[kk][ty*4];
      float4 b4 = *(const float4*)&Bs[kk][tx*4];
      float av[4] = {a4.x, a4.y, a4.z, a4.w};
      float bv[4] = {b4.x, b4.y, b4.z, b4.w};
      #pragma unroll
      for (int r = 0; r < 4; r++){
        #pragma unroll
        for (int c = 0; c < 4; c++) acc[r][c] = fmaf(av[r], bv[c], acc[r][c]);
      }
    }
    __syncthreads();
  }
  #pragma unroll
  for (int r = 0; r < 4; r++){
    #pragma unroll
    for (int c = 0; c < 4; c++){
      int i = i0 + ty*4 + r, j = j0 + tx*4 + c;
      float v = xx[i] + xx[j] - 2.0f * acc[r][c];
      v = (v > 0.0f) ? v : 0.0f;   // force +0.0 (never -0.0) for key encoding
      D[(size_t)i * N + j] = v;
    }
  }
}

// ---------------- top-21 per row (stable: value, then index) ----------------
__global__ __launch_bounds__(256) void topk_kernel(const float* __restrict__ D, int* __restrict__ T){
  int i = blockIdx.x, t = threadIdx.x;
  __shared__ float vals[N];
  __shared__ u64 wred[4];
  const float* row = D + (size_t)i * N;
  #pragma unroll
  for (int q = 0; q < 4; q++) vals[t + q*256] = row[t + q*256];
  __syncthreads();
  for (int it = 0; it < 21; ++it){
    u64 key = ~0ull;
    #pragma unroll
    for (int q = 0; q < 4; q++){
      int l = t + q*256;
      u64 k = ((u64)__float_as_uint(vals[l]) << 32) | (unsigned)l;
      key = umin64(key, k);
    }
    #pragma unroll
    for (int off = 32; off > 0; off >>= 1) key = umin64(key, __shfl_down(key, off));
    if ((t & 63) == 0) wred[t >> 6] = key;
    __syncthreads();
    if (t == 0){
      u64 b = umin64(umin64(wred[0], wred[1]), umin64(wred[2], wred[3]));
      int idx = (int)(b & 0xffffffffull);
      T[i*21 + it] = idx;
      vals[idx] = __int_as_float(0x7f800000);  // +inf, remove from later picks
    }
    __syncthreads();
  }
}

// ---------------- reciprocal masks (K: k=20, Khalf: k=10) ----------------
__global__ __launch_bounds__(64) void recip_kernel(const int* __restrict__ T,
                                                   u64* __restrict__ Kb, u64* __restrict__ Khb){
  int i = blockIdx.x, t = threadIdx.x;
  __shared__ u64 kb[16], khb[16];
  if (t < 16){ kb[t] = 0; khb[t] = 0; }
  __syncthreads();
  if (t < 21){
    int j = T[i*21 + t];
    bool r21 = false, r11 = false;
    for (int p = 0; p < 21; p++){
      if (T[j*21 + p] == i){ r21 = true; if (p < 11) r11 = true; }
    }
    if (r21) atomicOr(&kb[j >> 6], 1ull << (j & 63));
    if (t < 11 && r11) atomicOr(&khb[j >> 6], 1ull << (j & 63));
  }
  __syncthreads();
  if (t < 16){ Kb[i*16 + t] = kb[t]; Khb[i*16 + t] = khb[t]; }
}

// ---------------- query expansion: E = K | OR_{j in expand(i)} Khalf[j] ----------------
__global__ __launch_bounds__(256) void expand_kernel(const u64* __restrict__ Kb,
                                                     const u64* __restrict__ Khb,
                                                     u64* __restrict__ Eb){
  int i = blockIdx.x * blockDim.x + threadIdx.x;
  if (i >= N) return;
  u64 kr[16], er[16];
  #pragma unroll
  for (int w = 0; w < 16; w++){ kr[w] = Kb[i*16 + w]; er[w] = kr[w]; }
  #pragma unroll
  for (int w = 0; w < 16; w++){
    u64 b = kr[w];
    while (b){
      int bit = __ffsll((long long)b) - 1;
      b &= b - 1;
      int j = w*64 + bit;
      int inter = 0, sz = 0;
      #pragma unroll
      for (int ww = 0; ww < 16; ww++){
        u64 kh = Khb[j*16 + ww];
        inter += __popcll(kr[ww] & kh);
        sz += __popcll(kh);
      }
      if (3*inter > 2*sz){  // == inter > (2/3)*sz in the reference's fp32 arithmetic
        #pragma unroll
        for (int ww = 0; ww < 16; ww++) er[ww] |= Khb[j*16 + ww];
      }
    }
  }
  #pragma unroll
  for (int w = 0; w < 16; w++) Eb[i*16 + w] = er[w];
}

// ---------------- V = rownorm(exp(-D0) * E) ----------------
__global__ __launch_bounds__(256) void v_kernel(const float* __restrict__ Dm,
                                                const u64* __restrict__ Eb,
                                                float* __restrict__ V){
  int i = blockIdx.x, t = threadIdx.x;
  float w[4];
  #pragma unroll
  for (int q = 0; q < 4; q++){
    int l = t + q*256;
    u64 word = Eb[i*16 + (l >> 6)];
    float e = expf(-Dm[(size_t)i * N + l]);
    w[q] = ((word >> (l & 63)) & 1ull) ? e : 0.f;
  }
  float s = w[0] + w[1] + w[2] + w[3];
  #pragma unroll
  for (int off = 32; off > 0; off >>= 1) s += __shfl_down(s, off);
  __shared__ float sm[4];
  __shared__ float stot;
  if ((t & 63) == 0) sm[t >> 6] = s;
  __syncthreads();
  if (t == 0){ float S = sm[0] + sm[1] + sm[2] + sm[3]; stot = (S == 0.f) ? 1.f : S; }
  __syncthreads();
  float denom = stot;
  #pragma unroll
  for (int q = 0; q < 4; q++){
    int l = t + q*256;
    V[(size_t)i * N + l] = w[q] / denom;
  }
}

// ---------------- Vbar[i] = mean of V over 6 nearest neighbors ----------------
__global__ __launch_bounds__(256) void vbar_kernel(const float* __restrict__ V,
                                                   const int* __restrict__ T,
                                                   float* __restrict__ Vb){
  int i = blockIdx.x, t = threadIdx.x;
  int t6[6];
  #pragma unroll
  for (int p = 0; p < 6; p++) t6[p] = T[i*21 + p];
  #pragma unroll
  for (int q = 0; q < 4; q++){
    int l = t + q*256;
    float s = 0.f;
    #pragma unroll
    for (int p = 0; p < 6; p++) s += V[(size_t)t6[p] * N + l];
    Vb[(size_t)i * N + l] = s / 6.0f;
  }
}

// ---------------- jaccard "GEMM" (min-accumulate) + blend with D0, in place ----------------
__global__ __launch_bounds__(256) void jac_kernel(const float* __restrict__ Vb, float* __restrict__ Dm){
  __shared__ float As[32][68];
  __shared__ float Bs[32][68];
  int t = threadIdx.x;
  int tx = t & 15, ty = t >> 4;
  int i0 = blockIdx.y * 64, j0 = blockIdx.x * 64;
  float acc[4][4] = {};
  for (int k0 = 0; k0 < N; k0 += 32){
    #pragma unroll
    for (int e = 0; e < 8; e++){
      int idx = t + e*256;
      int r = idx >> 5, c = idx & 31;
      As[c][r] = Vb[(size_t)(i0 + r) * N + k0 + c];
      Bs[c][r] = Vb[(size_t)(j0 + r) * N + k0 + c];
    }
    __syncthreads();
    #pragma unroll
    for (int kk = 0; kk < 32; kk++){
      float4 a4 = *(const float4*)&As[kk][ty*4];
      float4 b4 = *(const float4*)&Bs[kk][tx*4];
      float av[4] = {a4.x, a4.y, a4.z, a4.w};
      float bv[4] = {b4.x, b4.y, b4.z, b4.w};
      #pragma unroll
      for (int r = 0; r < 4; r++){
        #pragma unroll
        for (int c = 0; c < 4; c++) acc[r][c] += fminf(av[r], bv[c]);
      }
    }
    __syncthreads();
  }
  #pragma unroll
  for (int r = 0; r < 4; r++){
    #pragma unroll
    for (int c = 0; c < 4; c++){
      int i = i0 + ty*4 + r, j = j0 + tx*4 + c;
      float tm = acc[r][c];
      float jac = 1.0f - tm / (2.0f - tm);
      size_t off = (size_t)i * N + j;
      Dm[off] = 0.7f * jac + 0.3f * Dm[off];
    }
  }
}

// ---------------- dist_ap / dist_an ----------------
__global__ __launch_bounds__(256) void apan_kernel(const float* __restrict__ Dm,
                                                   const int* __restrict__ tg,
                                                   float* __restrict__ ap, float* __restrict__ an){
  int i = blockIdx.x, t = threadIdx.x;
  int ti = tg[i];
  float mx = -3.402823466e38f, mn = 3.402823466e38f;
  #pragma unroll
  for (int q = 0; q < 4; q++){
    int l = t + q*256;
    float v = Dm[(size_t)i * N + l];
    if (tg[l] == ti) mx = fmaxf(mx, v); else mn = fminf(mn, v);
  }
  #pragma unroll
  for (int off = 32; off > 0; off >>= 1){
    mx = fmaxf(mx, __shfl_down(mx, off));
    mn = fminf(mn, __shfl_down(mn, off));
  }
  __shared__ float smx[4], smn[4];
  if ((t & 63) == 0){ smx[t >> 6] = mx; smn[t >> 6] = mn; }
  __syncthreads();
  if (t == 0){
    ap[i] = fmaxf(fmaxf(smx[0], smx[1]), fmaxf(smx[2], smx[3]));
    an[i] = fminf(fminf(smn[0], smn[1]), fminf(smn[2], smn[3]));
  }
}

// ---------------- loss = mean(relu(ap - an + margin)) ----------------
__global__ __launch_bounds__(256) void loss_kernel(const float* __restrict__ ap,
                                                   const float* __restrict__ an,
                                                   float* __restrict__ out){
  int t = threadIdx.x;
  float s = 0.f;
  #pragma unroll
  for (int q = 0; q < 4; q++){
    int l = t + q*256;
    s += fmaxf(ap[l] - an[l] + 0.03f, 0.f);
  }
  #pragma unroll
  for (int off = 32; off > 0; off >>= 1) s += __shfl_down(s, off);
  __shared__ float sm[4];
  if ((t & 63) == 0) sm[t >> 6] = s;
  __syncthreads();
  if (t == 0) out[0] = (sm[0] + sm[1] + sm[2] + sm[3]) / 1024.0f;
}

// ---------------- launch ----------------
static const size_t XX_OFF  = 0;         // 1024 f32
static const size_t T_OFF   = 4096;      // 1024*21 i32
static const size_t KB_OFF  = 90112;     // 1024*16 u64
static const size_t KHB_OFF = 221184;    // 1024*16 u64
static const size_t EB_OFF  = 352256;    // 1024*16 u64
static const size_t V_OFF   = 483328;    // 1024*1024 f32
static const size_t VB_OFF  = 4677632;   // 1024*1024 f32
static const size_t WS_NEED = 8871936;

extern "C" void kernel_launch(void* const* d_in, const int* in_sizes, int n_in,
                              void* d_out, int out_size, void* d_ws, size_t ws_size,
                              hipStream_t stream){
  const float* x  = (const float*)d_in[0];
  const int*   tg = (const int*)d_in[1];
  float* out = (float*)d_out;
  char* ws = (char*)d_ws;
  if (ws_size < WS_NEED) return;

  float* xx  = (float*)(ws + XX_OFF);
  int*   T   = (int*)(ws + T_OFF);
  u64*   Kb  = (u64*)(ws + KB_OFF);
  u64*   Khb = (u64*)(ws + KHB_OFF);
  u64*   Eb  = (u64*)(ws + EB_OFF);
  float* V   = (float*)(ws + V_OFF);
  float* Vb  = (float*)(ws + VB_OFF);

  float* dist = out + 1;          // n*n, holds D0 then final (in-place blend)
  float* ap   = out + 1 + (size_t)N*N;
  float* an   = ap + N;

  rownorm_kernel  <<<N, 256, 0, stream>>>(x, xx);
  gemm_dist_kernel<<<dim3(16,16), 256, 0, stream>>>(x, xx, dist);
  topk_kernel     <<<N, 256, 0, stream>>>(dist, T);
  recip_kernel    <<<N, 64, 0, stream>>>(T, Kb, Khb);
  expand_kernel   <<<4, 256, 0, stream>>>(Kb, Khb, Eb);
  v_kernel        <<<N, 256, 0, stream>>>(dist, Eb, V);
  vbar_kernel     <<<N, 256, 0, stream>>>(V, T, Vb);
  jac_kernel      <<<dim3(16,16), 256, 0, stream>>>(Vb, dist);
  apan_kernel     <<<N, 256, 0, stream>>>(dist, tg, ap, an);
  loss_kernel     <<<1, 256, 0, stream>>>(ap, an, out);
}

// Round 2
// 271.302 us; speedup vs baseline: 1.4002x; 1.4002x over previous
//
#include <hip/hip_runtime.h>

#define N 1024
#define DIM 2048

typedef unsigned long long u64;

__device__ __forceinline__ u64 umin64(u64 a, u64 b){ return a < b ? a : b; }

// ---------------- row norms ----------------
__global__ __launch_bounds__(256) void rownorm_kernel(const float* __restrict__ x, float* __restrict__ xx){
  int i = blockIdx.x, t = threadIdx.x;
  const float4* row = (const float4*)(x + (size_t)i * DIM);
  float s = 0.f;
  #pragma unroll
  for (int q = 0; q < 2; q++){
    float4 v = row[t + q*256];
    s += v.x*v.x + v.y*v.y + v.z*v.z + v.w*v.w;
  }
  #pragma unroll
  for (int off = 32; off > 0; off >>= 1) s += __shfl_down(s, off);
  __shared__ float sm[4];
  if ((t & 63) == 0) sm[t >> 6] = s;
  __syncthreads();
  if (t == 0) xx[i] = sm[0] + sm[1] + sm[2] + sm[3];
}

// ---------------- D0 = clamp(xx_i + xx_j - 2*x@x^T, 0) ----------------
// 64x32 tile, 512 blocks, float4 global loads, swizzled LDS.
// Per-element fmaf chain is ascending k, identical to the round-1 kernel -> D bit-identical.
__global__ __launch_bounds__(256) void gemm_dist_kernel(const float* __restrict__ x,
                                                        const float* __restrict__ xx,
                                                        float* __restrict__ D){
  __shared__ __align__(16) float As[32][64];   // [k][i-row], col' = col ^ ((k>>2)<<3)
  __shared__ __align__(16) float Bs[32][32];   // [k][j-row], col' = col ^ (((k>>2)&3)<<3)
  int t = threadIdx.x;
  int tx = t & 15, ty = t >> 4;
  int i0 = blockIdx.y * 64, j0 = blockIdx.x * 32;
  float acc[4][2] = {};
  for (int k0 = 0; k0 < DIM; k0 += 32){
    // A tile: 64 rows x 32 k = 512 float4 -> 2 per thread
    #pragma unroll
    for (int e = 0; e < 2; e++){
      int idx = t + e*256;
      int row = idx >> 3, kq = idx & 7;
      float4 f = *(const float4*)&x[(size_t)(i0+row)*DIM + k0 + kq*4];
      int sw = kq << 3;
      float v[4] = {f.x, f.y, f.z, f.w};
      #pragma unroll
      for (int e2 = 0; e2 < 4; e2++) As[kq*4+e2][row ^ sw] = v[e2];
    }
    // B tile: 32 rows x 32 k = 256 float4 -> 1 per thread
    {
      int row = t >> 3, kq = t & 7;
      float4 f = *(const float4*)&x[(size_t)(j0+row)*DIM + k0 + kq*4];
      int sw = (kq & 3) << 3;
      float v[4] = {f.x, f.y, f.z, f.w};
      #pragma unroll
      for (int e2 = 0; e2 < 4; e2++) Bs[kq*4+e2][row ^ sw] = v[e2];
    }
    __syncthreads();
    #pragma unroll
    for (int kk = 0; kk < 32; kk++){
      int swa = (kk >> 2) << 3;
      int swb = ((kk >> 2) & 3) << 3;
      float4 a4 = *(const float4*)&As[kk][(ty*4) ^ swa];
      float2 b2 = *(const float2*)&Bs[kk][(tx*2) ^ swb];
      float av[4] = {a4.x, a4.y, a4.z, a4.w};
      float bv[2] = {b2.x, b2.y};
      #pragma unroll
      for (int r = 0; r < 4; r++){
        #pragma unroll
        for (int c = 0; c < 2; c++) acc[r][c] = fmaf(av[r], bv[c], acc[r][c]);
      }
    }
    __syncthreads();
  }
  #pragma unroll
  for (int r = 0; r < 4; r++){
    #pragma unroll
    for (int c = 0; c < 2; c++){
      int i = i0 + ty*4 + r, j = j0 + tx*2 + c;
      float v = xx[i] + xx[j] - 2.0f * acc[r][c];
      v = (v > 0.0f) ? v : 0.0f;   // force +0.0 for key encoding
      D[(size_t)i * N + j] = v;
    }
  }
}

// ---------------- top-21 per row (stable: value, then index) ----------------
__global__ __launch_bounds__(256) void topk_kernel(const float* __restrict__ D, int* __restrict__ T){
  int i = blockIdx.x, t = threadIdx.x;
  __shared__ float vals[N];
  __shared__ u64 wred[4];
  const float* row = D + (size_t)i * N;
  #pragma unroll
  for (int q = 0; q < 4; q++) vals[t + q*256] = row[t + q*256];
  __syncthreads();
  for (int it = 0; it < 21; ++it){
    u64 key = ~0ull;
    #pragma unroll
    for (int q = 0; q < 4; q++){
      int l = t + q*256;
      u64 k = ((u64)__float_as_uint(vals[l]) << 32) | (unsigned)l;
      key = umin64(key, k);
    }
    #pragma unroll
    for (int off = 32; off > 0; off >>= 1) key = umin64(key, __shfl_down(key, off));
    if ((t & 63) == 0) wred[t >> 6] = key;
    __syncthreads();
    if (t == 0){
      u64 b = umin64(umin64(wred[0], wred[1]), umin64(wred[2], wred[3]));
      int idx = (int)(b & 0xffffffffull);
      T[i*21 + it] = idx;
      vals[idx] = __int_as_float(0x7f800000);
    }
    __syncthreads();
  }
}

// ---------------- reciprocal masks (K: k=20, Khalf: k=10) ----------------
__global__ __launch_bounds__(64) void recip_kernel(const int* __restrict__ T,
                                                   u64* __restrict__ Kb, u64* __restrict__ Khb){
  int i = blockIdx.x, t = threadIdx.x;
  __shared__ u64 kb[16], khb[16];
  if (t < 16){ kb[t] = 0; khb[t] = 0; }
  __syncthreads();
  if (t < 21){
    int j = T[i*21 + t];
    bool r21 = false, r11 = false;
    for (int p = 0; p < 21; p++){
      if (T[j*21 + p] == i){ r21 = true; if (p < 11) r11 = true; }
    }
    if (r21) atomicOr(&kb[j >> 6], 1ull << (j & 63));
    if (t < 11 && r11) atomicOr(&khb[j >> 6], 1ull << (j & 63));
  }
  __syncthreads();
  if (t < 16){ Kb[i*16 + t] = kb[t]; Khb[i*16 + t] = khb[t]; }
}

// ---------------- query expansion ----------------
__global__ __launch_bounds__(256) void expand_kernel(const u64* __restrict__ Kb,
                                                     const u64* __restrict__ Khb,
                                                     u64* __restrict__ Eb){
  int i = blockIdx.x * blockDim.x + threadIdx.x;
  if (i >= N) return;
  u64 kr[16], er[16];
  #pragma unroll
  for (int w = 0; w < 16; w++){ kr[w] = Kb[i*16 + w]; er[w] = kr[w]; }
  #pragma unroll
  for (int w = 0; w < 16; w++){
    u64 b = kr[w];
    while (b){
      int bit = __ffsll((long long)b) - 1;
      b &= b - 1;
      int j = w*64 + bit;
      int inter = 0, sz = 0;
      #pragma unroll
      for (int ww = 0; ww < 16; ww++){
        u64 kh = Khb[j*16 + ww];
        inter += __popcll(kr[ww] & kh);
        sz += __popcll(kh);
      }
      if (3*inter > 2*sz){
        #pragma unroll
        for (int ww = 0; ww < 16; ww++) er[ww] |= Khb[j*16 + ww];
      }
    }
  }
  #pragma unroll
  for (int w = 0; w < 16; w++) Eb[i*16 + w] = er[w];
}

// ---------------- V = rownorm(exp(-D0) * E) ----------------
__global__ __launch_bounds__(256) void v_kernel(const float* __restrict__ Dm,
                                                const u64* __restrict__ Eb,
                                                float* __restrict__ V){
  int i = blockIdx.x, t = threadIdx.x;
  float w[4];
  #pragma unroll
  for (int q = 0; q < 4; q++){
    int l = t + q*256;
    u64 word = Eb[i*16 + (l >> 6)];
    float e = expf(-Dm[(size_t)i * N + l]);
    w[q] = ((word >> (l & 63)) & 1ull) ? e : 0.f;
  }
  float s = w[0] + w[1] + w[2] + w[3];
  #pragma unroll
  for (int off = 32; off > 0; off >>= 1) s += __shfl_down(s, off);
  __shared__ float sm[4];
  __shared__ float stot;
  if ((t & 63) == 0) sm[t >> 6] = s;
  __syncthreads();
  if (t == 0){ float S = sm[0] + sm[1] + sm[2] + sm[3]; stot = (S == 0.f) ? 1.f : S; }
  __syncthreads();
  float denom = stot;
  #pragma unroll
  for (int q = 0; q < 4; q++){
    int l = t + q*256;
    V[(size_t)i * N + l] = w[q] / denom;
  }
}

// ---------------- Vbar[i] = mean of V over 6 nearest neighbors ----------------
__global__ __launch_bounds__(256) void vbar_kernel(const float* __restrict__ V,
                                                   const int* __restrict__ T,
                                                   float* __restrict__ Vb){
  int i = blockIdx.x, t = threadIdx.x;
  int t6[6];
  #pragma unroll
  for (int p = 0; p < 6; p++) t6[p] = T[i*21 + p];
  #pragma unroll
  for (int q = 0; q < 4; q++){
    int l = t + q*256;
    float s = 0.f;
    #pragma unroll
    for (int p = 0; p < 6; p++) s += V[(size_t)t6[p] * N + l];
    Vb[(size_t)i * N + l] = s / 6.0f;
  }
}

// ---------------- jaccard min-accumulate, split-K partials ----------------
__global__ __launch_bounds__(256) void jac_split_kernel(const float* __restrict__ Vb,
    float* __restrict__ p0, float* __restrict__ p1, float* __restrict__ p2, float* __restrict__ p3,
    int kc){
  __shared__ __align__(16) float As[32][64];
  __shared__ __align__(16) float Bs[32][64];
  int t = threadIdx.x;
  int tx = t & 15, ty = t >> 4;
  int i0 = blockIdx.y * 64, j0 = blockIdx.x * 64;
  int kbase = blockIdx.z * kc;
  float acc[4][4] = {};
  for (int k0 = kbase; k0 < kbase + kc; k0 += 32){
    #pragma unroll
    for (int e = 0; e < 2; e++){
      int idx = t + e*256;
      int row = idx >> 3, kq = idx & 7;
      float4 fa = *(const float4*)&Vb[(size_t)(i0+row)*N + k0 + kq*4];
      float4 fb = *(const float4*)&Vb[(size_t)(j0+row)*N + k0 + kq*4];
      int sw = kq << 3;
      float va[4] = {fa.x, fa.y, fa.z, fa.w};
      float vb[4] = {fb.x, fb.y, fb.z, fb.w};
      #pragma unroll
      for (int e2 = 0; e2 < 4; e2++){
        As[kq*4+e2][row ^ sw] = va[e2];
        Bs[kq*4+e2][row ^ sw] = vb[e2];
      }
    }
    __syncthreads();
    #pragma unroll
    for (int kk = 0; kk < 32; kk++){
      int sw = (kk >> 2) << 3;
      float4 a4 = *(const float4*)&As[kk][(ty*4) ^ sw];
      float4 b4 = *(const float4*)&Bs[kk][(tx*4) ^ sw];
      float av[4] = {a4.x, a4.y, a4.z, a4.w};
      float bv[4] = {b4.x, b4.y, b4.z, b4.w};
      #pragma unroll
      for (int r = 0; r < 4; r++){
        #pragma unroll
        for (int c = 0; c < 4; c++) acc[r][c] += fminf(av[r], bv[c]);
      }
    }
    __syncthreads();
  }
  float* P = (blockIdx.z == 0) ? p0 : (blockIdx.z == 1) ? p1 : (blockIdx.z == 2) ? p2 : p3;
  #pragma unroll
  for (int r = 0; r < 4; r++){
    #pragma unroll
    for (int c = 0; c < 4; c++){
      int i = i0 + ty*4 + r, j = j0 + tx*4 + c;
      P[(size_t)i * N + j] = acc[r][c];
    }
  }
}

// ---------------- combine partials -> jac -> blend with D0 in place ----------------
__global__ __launch_bounds__(256) void jac_combine_kernel(
    const float* __restrict__ p0, const float* __restrict__ p1,
    const float* __restrict__ p2, const float* __restrict__ p3,
    int nsplit, float* __restrict__ Dm){
  size_t idx = ((size_t)blockIdx.x * 256 + threadIdx.x) * 4;
  float4 s = *(const float4*)&p0[idx];
  if (nsplit > 1){
    float4 q = *(const float4*)&p1[idx];
    s.x += q.x; s.y += q.y; s.z += q.z; s.w += q.w;
  }
  if (nsplit > 2){
    float4 q = *(const float4*)&p2[idx];
    s.x += q.x; s.y += q.y; s.z += q.z; s.w += q.w;
    q = *(const float4*)&p3[idx];
    s.x += q.x; s.y += q.y; s.z += q.z; s.w += q.w;
  }
  float4 d0 = *(const float4*)&Dm[idx];
  float4 o;
  o.x = 0.7f * (1.0f - s.x / (2.0f - s.x)) + 0.3f * d0.x;
  o.y = 0.7f * (1.0f - s.y / (2.0f - s.y)) + 0.3f * d0.y;
  o.z = 0.7f * (1.0f - s.z / (2.0f - s.z)) + 0.3f * d0.z;
  o.w = 0.7f * (1.0f - s.w / (2.0f - s.w)) + 0.3f * d0.w;
  *(float4*)&Dm[idx] = o;
}

// ---------------- dist_ap / dist_an ----------------
__global__ __launch_bounds__(256) void apan_kernel(const float* __restrict__ Dm,
                                                   const int* __restrict__ tg,
                                                   float* __restrict__ ap, float* __restrict__ an){
  int i = blockIdx.x, t = threadIdx.x;
  int ti = tg[i];
  float mx = -3.402823466e38f, mn = 3.402823466e38f;
  #pragma unroll
  for (int q = 0; q < 4; q++){
    int l = t + q*256;
    float v = Dm[(size_t)i * N + l];
    if (tg[l] == ti) mx = fmaxf(mx, v); else mn = fminf(mn, v);
  }
  #pragma unroll
  for (int off = 32; off > 0; off >>= 1){
    mx = fmaxf(mx, __shfl_down(mx, off));
    mn = fminf(mn, __shfl_down(mn, off));
  }
  __shared__ float smx[4], smn[4];
  if ((t & 63) == 0){ smx[t >> 6] = mx; smn[t >> 6] = mn; }
  __syncthreads();
  if (t == 0){
    ap[i] = fmaxf(fmaxf(smx[0], smx[1]), fmaxf(smx[2], smx[3]));
    an[i] = fminf(fminf(smn[0], smn[1]), fminf(smn[2], smn[3]));
  }
}

// ---------------- loss ----------------
__global__ __launch_bounds__(256) void loss_kernel(const float* __restrict__ ap,
                                                   const float* __restrict__ an,
                                                   float* __restrict__ out){
  int t = threadIdx.x;
  float s = 0.f;
  #pragma unroll
  for (int q = 0; q < 4; q++){
    int l = t + q*256;
    s += fmaxf(ap[l] - an[l] + 0.03f, 0.f);
  }
  #pragma unroll
  for (int off = 32; off > 0; off >>= 1) s += __shfl_down(s, off);
  __shared__ float sm[4];
  if ((t & 63) == 0) sm[t >> 6] = s;
  __syncthreads();
  if (t == 0) out[0] = (sm[0] + sm[1] + sm[2] + sm[3]) / 1024.0f;
}

// ---------------- launch ----------------
static const size_t XX_OFF  = 0;          // 1024 f32
static const size_t T_OFF   = 4096;       // 1024*21 i32
static const size_t KB_OFF  = 90112;      // 1024*16 u64
static const size_t KHB_OFF = 221184;
static const size_t EB_OFF  = 352256;
static const size_t V_OFF   = 483328;     // 1024*1024 f32 (reused as jac partial 0)
static const size_t VB_OFF  = 4677632;    // 1024*1024 f32
static const size_t P1_OFF  = 8871936;    // jac partials 1..3
static const size_t WS_BASE = 8871936;
static const size_t WS2     = 13066240;   // WS_BASE + 4MB
static const size_t WS4     = 21454848;   // WS_BASE + 12MB

extern "C" void kernel_launch(void* const* d_in, const int* in_sizes, int n_in,
                              void* d_out, int out_size, void* d_ws, size_t ws_size,
                              hipStream_t stream){
  const float* x  = (const float*)d_in[0];
  const int*   tg = (const int*)d_in[1];
  float* out = (float*)d_out;
  char* ws = (char*)d_ws;
  if (ws_size < WS_BASE) return;

  float* xx  = (float*)(ws + XX_OFF);
  int*   T   = (int*)(ws + T_OFF);
  u64*   Kb  = (u64*)(ws + KB_OFF);
  u64*   Khb = (u64*)(ws + KHB_OFF);
  u64*   Eb  = (u64*)(ws + EB_OFF);
  float* V   = (float*)(ws + V_OFF);
  float* Vb  = (float*)(ws + VB_OFF);

  float* dist = out + 1;
  float* ap   = out + 1 + (size_t)N*N;
  float* an   = ap + N;

  int nsplit = (ws_size >= WS4) ? 4 : (ws_size >= WS2) ? 2 : 1;
  float* P0 = V;                              // V is dead after vbar_kernel
  float* P1 = (nsplit > 1) ? (float*)(ws + P1_OFF) : P0;
  float* P2 = (nsplit > 2) ? (float*)(ws + P1_OFF + (size_t)N*N*4) : P0;
  float* P3 = (nsplit > 2) ? (float*)(ws + P1_OFF + (size_t)N*N*8) : P0;

  rownorm_kernel  <<<N, 256, 0, stream>>>(x, xx);
  gemm_dist_kernel<<<dim3(32,16), 256, 0, stream>>>(x, xx, dist);
  topk_kernel     <<<N, 256, 0, stream>>>(dist, T);
  recip_kernel    <<<N, 64, 0, stream>>>(T, Kb, Khb);
  expand_kernel   <<<4, 256, 0, stream>>>(Kb, Khb, Eb);
  v_kernel        <<<N, 256, 0, stream>>>(dist, Eb, V);
  vbar_kernel     <<<N, 256, 0, stream>>>(V, T, Vb);
  jac_split_kernel<<<dim3(16,16,nsplit), 256, 0, stream>>>(Vb, P0, P1, P2, P3, N/nsplit);
  jac_combine_kernel<<<1024, 256, 0, stream>>>(P0, P1, P2, P3, nsplit, dist);
  apan_kernel     <<<N, 256, 0, stream>>>(dist, tg, ap, an);
  loss_kernel     <<<1, 256, 0, stream>>>(ap, an, out);
}